// Round 1
// baseline (18175.821 us; speedup 1.0000x reference)
//
#include <hip/hip_runtime.h>
#include <math.h>

#define SEQ   512
#define BATCH 64
#define HID   512
#define NROW  1536                     // 3 gates * HID rows
#define XROW_FLOATS ((size_t)SEQ * NROW * BATCH)   // 50,331,648 floats = 201.3 MB
#define HBUF_FLOATS (2 * HID * BATCH)              // double-buffered h, [buf][k][b]
#define SBH ((size_t)SEQ * BATCH * HID)

__device__ __forceinline__ float sigf(float x) {
    return 1.f / (1.f + __expf(-x));
}
__device__ __forceinline__ float tanh_fast(float x) {
    float ax = fabsf(x);
    float e = __expf(-2.f * ax);
    float r = (1.f - e) / (1.f + e);
    return copysignf(r, x);
}

// ---------------- Phase 1: xrow[t][gate*512+j][b] = dot(x[t,b,:], Wx[g][j,:]) ----------------
// One workgroup per t. LDS: xT [256][65] (k-half, pad 65 for transpose), per-wave W tile [8][256].
__global__ __launch_bounds__(256) void xproj_kernel(
    const float* __restrict__ x, const float* __restrict__ Wxi,
    const float* __restrict__ Wxc, const float* __restrict__ Wxo,
    float* __restrict__ xrow)
{
    extern __shared__ float lds[];
    float* xT = lds;                              // [256][65]
    const int tid = threadIdx.x, lane = tid & 63, wv = tid >> 6;
    float* wl = lds + 256 * 65 + wv * (8 * 256);  // per-wave [8 rows][256 k]
    const int t = blockIdx.x;

    for (int kh = 0; kh < 2; ++kh) {
        __syncthreads();  // protect xT from prior-half readers
        // stage x[t, b, kh*256 .. +256) transposed into xT[k][b]
        for (int b = wv; b < 64; b += 4) {
            const float* xp = x + ((size_t)t * 64 + b) * 512 + kh * 256;
            #pragma unroll
            for (int q = 0; q < 4; ++q) {
                int k = lane + q * 64;
                xT[k * 65 + b] = xp[k];   // banks (k+b)%32: conflict-free
            }
        }
        __syncthreads();

        for (int m = 0; m < 48; ++m) {
            const int Bk = wv + 4 * m;        // row-block 0..191
            const int R0 = Bk * 8;
            // stage this wave's 8 weight rows (k-half) into its private LDS tile
            #pragma unroll
            for (int r = 0; r < 8; ++r) {
                const int R = R0 + r, g = R >> 9, j = R & 511;
                const float* wsrc = (g == 0) ? Wxi : ((g == 1) ? Wxc : Wxo);
                const float4 w4 = *(const float4*)(wsrc + (size_t)j * 512 + kh * 256 + lane * 4);
                *(float4*)(wl + r * 256 + lane * 4) = w4;
            }
            float acc[8] = {0.f, 0.f, 0.f, 0.f, 0.f, 0.f, 0.f, 0.f};
            #pragma unroll 2
            for (int c = 0; c < 64; ++c) {
                const float x0 = xT[(4 * c + 0) * 65 + lane];
                const float x1 = xT[(4 * c + 1) * 65 + lane];
                const float x2 = xT[(4 * c + 2) * 65 + lane];
                const float x3 = xT[(4 * c + 3) * 65 + lane];
                #pragma unroll
                for (int r = 0; r < 8; ++r) {
                    const float4 w4 = *(const float4*)(wl + r * 256 + c * 4);
                    acc[r] += x0 * w4.x + x1 * w4.y + x2 * w4.z + x3 * w4.w;
                }
            }
            #pragma unroll
            for (int r = 0; r < 8; ++r) {
                const size_t o = ((size_t)t * NROW + R0 + r) * 64 + lane;
                if (kh) xrow[o] += acc[r];   // same thread both halves; syncthreads drained stores
                else    xrow[o]  = acc[r];
            }
        }
    }
}

// ---------------- Phase 2: persistent cooperative scan ----------------
// 128 wgs x 512 thr; wg owns j-slice of 4 (x3 gates = 12 rows, weights LDS-resident).
// 8 waves: wave = (w = wv&3 -> rows 3w..3w+2, kh = wv>>2 -> k half). One 2-level
// device barrier per step; h exchanged via agent-scope atomics (XCD-L2-safe).
__global__ __launch_bounds__(512) void scan_kernel(
    const float* __restrict__ xrow,
    const float* __restrict__ Whi, const float* __restrict__ Whc, const float* __restrict__ Who,
    const float* __restrict__ bi, const float* __restrict__ bc, const float* __restrict__ bo,
    float* __restrict__ hbuf, unsigned* __restrict__ bar, float* __restrict__ out)
{
    extern __shared__ float lds[];
    float* hT   = lds;                        // [512][64]  (2-way bank alias: free)
    float* wl   = lds + 32768;                // [12][512]
    float* gbuf = lds + 32768 + 6144;         // [12][2][64] partial pre-activations
    float* bias = lds + 32768 + 6144 + 1536;  // [12]
    const int tid = threadIdx.x, lane = tid & 63, wv = tid >> 6;
    const int w = wv & 3, kh = wv >> 2;
    const int wg = blockIdx.x, j0 = wg * 4;

    // stage recurrent weights (12 rows) + biases, once
    for (int idx = tid; idx < 12 * 512; idx += 512) {
        const int r = idx >> 9, k = idx & 511, g = r >> 2, jj = r & 3;
        const float* wsrc = (g == 0) ? Whi : ((g == 1) ? Whc : Who);
        wl[idx] = wsrc[(size_t)(j0 + jj) * 512 + k];
    }
    if (tid < 12) {
        const int g = tid >> 2, jj = tid & 3;
        const float* bb = (g == 0) ? bi : ((g == 1) ? bc : bo);
        bias[tid] = bb[j0 + jj];
    }
    const int ub = tid >> 2, ujj = tid & 3;   // update mapping: jj fast -> 16B out segments
    float creg = 0.f;                          // c-state lives in a register (tid<256)
    __syncthreads();

    const int r0 = 3 * w;
    for (int t = 0; t < SEQ; ++t) {
        // ---- stage h_{t} (agent-scope loads: bypass non-coherent per-XCD L2) ----
        const float* hsrc = hbuf + (size_t)(t & 1) * 32768;
        for (int i = tid; i < 32768; i += 512)
            hT[i] = __hip_atomic_load(hsrc + i, __ATOMIC_RELAXED, __HIP_MEMORY_SCOPE_AGENT);
        __syncthreads();

        // ---- gate pre-activations: 3 rows x 64 batches per wave, half-K ----
        float a0, a1, a2;
        if (kh == 0) {
            const size_t xb = ((size_t)t * NROW) * 64 + lane;
            a0 = bias[r0 + 0] + xrow[xb + (size_t)((((r0 + 0) >> 2) * 512) + j0 + ((r0 + 0) & 3)) * 64];
            a1 = bias[r0 + 1] + xrow[xb + (size_t)((((r0 + 1) >> 2) * 512) + j0 + ((r0 + 1) & 3)) * 64];
            a2 = bias[r0 + 2] + xrow[xb + (size_t)((((r0 + 2) >> 2) * 512) + j0 + ((r0 + 2) & 3)) * 64];
        } else { a0 = a1 = a2 = 0.f; }

        const float* hk  = hT + kh * 16384;
        const float* w0p = wl + (r0 + 0) * 512 + kh * 256;
        const float* w1p = wl + (r0 + 1) * 512 + kh * 256;
        const float* w2p = wl + (r0 + 2) * 512 + kh * 256;
        #pragma unroll 4
        for (int c = 0; c < 64; ++c) {
            const float h0 = hk[(4 * c + 0) * 64 + lane];
            const float h1 = hk[(4 * c + 1) * 64 + lane];
            const float h2 = hk[(4 * c + 2) * 64 + lane];
            const float h3 = hk[(4 * c + 3) * 64 + lane];
            const float4 w0 = *(const float4*)(w0p + 4 * c);
            const float4 w1 = *(const float4*)(w1p + 4 * c);
            const float4 w2 = *(const float4*)(w2p + 4 * c);
            a0 += h0 * w0.x + h1 * w0.y + h2 * w0.z + h3 * w0.w;
            a1 += h0 * w1.x + h1 * w1.y + h2 * w1.z + h3 * w1.w;
            a2 += h0 * w2.x + h1 * w2.y + h2 * w2.z + h3 * w2.w;
        }
        gbuf[(r0 + 0) * 128 + kh * 64 + lane] = a0;
        gbuf[(r0 + 1) * 128 + kh * 64 + lane] = a1;
        gbuf[(r0 + 2) * 128 + kh * 64 + lane] = a2;
        __syncthreads();

        // ---- elementwise update: thread = (b=ub, jj=ujj), c in register ----
        if (tid < 256) {
            const int rI = 0 * 4 + ujj, rC = 1 * 4 + ujj, rO = 2 * 4 + ujj;
            const float pi = gbuf[rI * 128 + ub] + gbuf[rI * 128 + 64 + ub];
            const float pc = gbuf[rC * 128 + ub] + gbuf[rC * 128 + 64 + ub];
            const float po = gbuf[rO * 128 + ub] + gbuf[rO * 128 + 64 + ub];
            const float it = sigf(pi);
            const float chv = tanh_fast(pc);
            const float ot = sigf(po);
            creg = (1.f - it) * creg + it * chv;          // coupled forget gate
            const float hn = ot * tanh_fast(creg);
            const int jg = j0 + ujj;
            __hip_atomic_store(hbuf + (size_t)((t + 1) & 1) * 32768 + jg * 64 + ub, hn,
                               __ATOMIC_RELAXED, __HIP_MEMORY_SCOPE_AGENT);
            out[((size_t)t * 64 + ub) * 512 + jg] = hn;
            if (t == SEQ - 1) {
                out[SBH + (size_t)ub * 512 + jg] = hn;            // h_T
                out[SBH + 32768 + (size_t)ub * 512 + jg] = creg;  // c_T
            }
        }
        __syncthreads();  // drains every wave's h-stores (vmcnt 0) before arrival

        // ---- 2-level device barrier: 8 groups of 16, monotonic counters ----
        if (tid == 0) {
            __threadfence();
            const int grp = wg >> 4;
            const unsigned old = __hip_atomic_fetch_add(bar + grp * 32, 1u,
                                     __ATOMIC_ACQ_REL, __HIP_MEMORY_SCOPE_AGENT);
            if (old == (unsigned)((t + 1) * 16 - 1))
                __hip_atomic_fetch_add(bar + 8 * 32, 1u,
                                     __ATOMIC_ACQ_REL, __HIP_MEMORY_SCOPE_AGENT);
            const unsigned tgt = (unsigned)((t + 1) * 8);
            while (__hip_atomic_load(bar + 8 * 32, __ATOMIC_RELAXED,
                                     __HIP_MEMORY_SCOPE_AGENT) < tgt)
                __builtin_amdgcn_s_sleep(1);
        }
        __syncthreads();
    }
}

extern "C" void kernel_launch(void* const* d_in, const int* in_sizes, int n_in,
                              void* d_out, int out_size, void* d_ws, size_t ws_size,
                              hipStream_t stream)
{
    const float* x   = (const float*)d_in[0];
    const float* Wxi = (const float*)d_in[1];
    const float* Whi = (const float*)d_in[2];
    const float* bi  = (const float*)d_in[3];
    const float* Wxc = (const float*)d_in[4];
    const float* Whc = (const float*)d_in[5];
    const float* bc  = (const float*)d_in[6];
    const float* Wxo = (const float*)d_in[7];
    const float* Who = (const float*)d_in[8];
    const float* bo  = (const float*)d_in[9];
    float* out = (float*)d_out;
    char* ws = (char*)d_ws;

    float*    xrow = (float*)ws;
    float*    hbuf = (float*)(ws + XROW_FLOATS * 4);
    unsigned* bar  = (unsigned*)(ws + XROW_FLOATS * 4 + (size_t)HBUF_FLOATS * 4);

    // zero h_0 double-buffer + barrier counters every call (ws is re-poisoned 0xAA)
    hipMemsetAsync(hbuf, 0, (size_t)HBUF_FLOATS * 4 + 4096, stream);

    hipLaunchKernelGGL(xproj_kernel, dim3(512), dim3(256), 99328, stream,
                       x, Wxi, Wxc, Wxo, xrow);
    hipLaunchKernelGGL(scan_kernel, dim3(128), dim3(512), 161840, stream,
                       xrow, Whi, Whc, Who, bi, bc, bo, hbuf, bar, out);
}